// Round 1
// baseline (537.263 us; speedup 1.0000x reference)
//
#include <hip/hip_runtime.h>
#include <cstdint>
#include <cstddef>

typedef unsigned short u16;
typedef __attribute__((ext_vector_type(8))) __bf16 bf16x8;
typedef __attribute__((ext_vector_type(4))) float f32x4;

#define SEQ 1024
#define MROWS 4096
#define DDIM 768
#define HID 769
#define KP1 800
#define MLPD 3072
#define KP2 3104
#define NHEADS 12

static __device__ __forceinline__ u16 f2bf(float f){
  union { float f; uint32_t u; } v; v.f = f;
  return (u16)((v.u + 0x7FFFu + ((v.u >> 16) & 1u)) >> 16);
}

static __device__ __forceinline__ f32x4 mfma16(bf16x8 a, bf16x8 b, f32x4 c){
  return __builtin_amdgcn_mfma_f32_16x16x32_bf16(a, b, c, 0, 0, 0);
}

static __device__ __forceinline__ void async_lds16(const u16* g, u16* l){
  u16* gm = const_cast<u16*>(g);
  __builtin_amdgcn_global_load_lds(
      (__attribute__((address_space(1))) void*)gm,
      (__attribute__((address_space(3))) void*)l, 16, 0, 0);
}

static __device__ __forceinline__ float blk_reduce(float v, float* red, int tid){
  #pragma unroll
  for (int off = 1; off < 64; off <<= 1) v += __shfl_xor(v, off, 64);
  __syncthreads();
  if ((tid & 63) == 0) red[tid >> 6] = v;
  __syncthreads();
  return red[0] + red[1] + red[2] + red[3];
}

// ---------------- weight fp32 -> bf16 with K padding ----------------
__global__ void convert_w(const float* __restrict__ W, u16* __restrict__ O,
                          int Nr, int K, int Kp){
  int idx = blockIdx.x * 256 + threadIdx.x;
  if (idx >= Nr * Kp) return;
  int n = idx / Kp, k = idx - n * Kp;
  O[idx] = (k < K) ? f2bf(W[(size_t)n * K + k]) : (u16)0;
}

// ---------------- lorentz layernorm -> bf16 [m][800] (col0 = t) -----
__global__ __launch_bounds__(256) void ln_kernel(const float* __restrict__ X, int xstr, int xoff,
    const float* __restrict__ g, const float* __restrict__ b, u16* __restrict__ O){
  __shared__ float red[4];
  int m = blockIdx.x, tid = threadIdx.x;
  const float* xr = X + (size_t)m * xstr + xoff;
  float s[3], y[3];
  float s1 = 0.f, s2 = 0.f;
  #pragma unroll
  for (int j = 0; j < 3; j++){ float v = xr[tid + j*256]; s[j] = v; s1 += v; s2 += v*v; }
  s1 = blk_reduce(s1, red, tid);
  s2 = blk_reduce(s2, red, tid);
  float mu = s1 * (1.f/768.f);
  float var = s2 * (1.f/768.f) - mu*mu;
  float rstd = rsqrtf(var + 1e-5f);
  float q = 0.f;
  #pragma unroll
  for (int j = 0; j < 3; j++){ int i = tid + j*256; y[j] = (s[j]-mu)*rstd*g[i] + b[i]; q += y[j]*y[j]; }
  q = blk_reduce(q, red, tid);
  u16* orow = O + (size_t)m * KP1;
  #pragma unroll
  for (int j = 0; j < 3; j++) orow[1 + tid + j*256] = f2bf(y[j]);
  if (tid == 0) orow[0] = f2bf(sqrtf(1.f + q));
  if (tid < 31) orow[769 + tid] = 0;
}

// ---------------- 128x128 bf16 GEMM, fp32 out, optional residual ----
// A [M][Kp] bf16, B [N][Kp] bf16 (= W as given, K contiguous), C [M][N] fp32
__global__ __launch_bounds__(256) void gemm128(
    const u16* __restrict__ A,
    const u16* __restrict__ B0, const u16* __restrict__ B1, const u16* __restrict__ B2,
    float* __restrict__ C, const float* __restrict__ R,
    int N, int Kp, int ldr, int roff)
{
  __shared__ u16 As[128*32];
  __shared__ u16 Bs[128*32];
  int tid = threadIdx.x;
  int wave = tid >> 6, lane = tid & 63;
  int lrow = lane & 15, lq = lane >> 4;
  int m0 = blockIdx.y * 128, n0 = blockIdx.x * 128;
  int wm = wave >> 1, wn = wave & 1;
  const u16* B = (blockIdx.z == 0) ? B0 : (blockIdx.z == 1 ? B1 : B2);
  C += (size_t)blockIdx.z * MROWS * N;
  f32x4 acc[4][4] = {};
  int seg = wave * 2;
  int srow = lane >> 2;        // 0..15
  int scol = (lane & 3) * 8;   // 0,8,16,24
  const u16* Abase = A + (size_t)m0 * Kp;
  const u16* Bbase = B + (size_t)n0 * Kp;
  for (int k0 = 0; k0 < Kp; k0 += 32){
    __syncthreads();
    #pragma unroll
    for (int i = 0; i < 2; i++){
      int s = seg + i;
      async_lds16(Abase + (size_t)(s*16 + srow) * Kp + k0 + scol, As + s*512);
      async_lds16(Bbase + (size_t)(s*16 + srow) * Kp + k0 + scol, Bs + s*512);
    }
    __syncthreads();
    bf16x8 af[4], bfr[4];
    #pragma unroll
    for (int t = 0; t < 4; t++){
      af[t]  = *(const bf16x8*)(As + (wm*64 + t*16 + lrow)*32 + lq*8);
      bfr[t] = *(const bf16x8*)(Bs + (wn*64 + t*16 + lrow)*32 + lq*8);
    }
    #pragma unroll
    for (int mt = 0; mt < 4; mt++)
      #pragma unroll
      for (int nt = 0; nt < 4; nt++)
        acc[mt][nt] = mfma16(af[mt], bfr[nt], acc[mt][nt]);
  }
  #pragma unroll
  for (int mt = 0; mt < 4; mt++){
    #pragma unroll
    for (int nt = 0; nt < 4; nt++){
      int col = n0 + wn*64 + nt*16 + lrow;
      #pragma unroll
      for (int r = 0; r < 4; r++){
        int row = m0 + wm*64 + mt*16 + lq*4 + r;
        float v = acc[mt][nt][r];
        if (R) v += R[(size_t)row * ldr + roff + col];
        C[(size_t)row * N + col] = v;
      }
    }
  }
}

// ---------------- pack Q/K heads: bf16 [bh][n][64] + t arrays -------
__global__ __launch_bounds__(256) void pack_qk(const float* __restrict__ raw,
    u16* __restrict__ Qp, u16* __restrict__ Kpk, float* __restrict__ qt, float* __restrict__ kt)
{
  int wave = threadIdx.x >> 6, lane = threadIdx.x & 63;
  int m = blockIdx.x * 4 + wave;
  int h = blockIdx.y;
  int which = blockIdx.z;
  const float* src = raw + (size_t)which * MROWS * DDIM + (size_t)m * DDIM + h*64 + lane;
  float v = *src;
  float ss = v*v;
  #pragma unroll
  for (int off = 1; off < 64; off <<= 1) ss += __shfl_xor(ss, off, 64);
  int b = m >> 10, n = m & 1023, bh = b * NHEADS + h;
  u16* dst = (which ? Kpk : Qp) + ((size_t)bh * SEQ + n) * 64 + lane;
  *dst = f2bf(v);
  if (lane == 0) (which ? kt : qt)[bh * SEQ + n] = sqrtf(1.f + ss);
}

// ---------------- pack V: logmap0, transposed bf16 [bh][dim][key] ---
__global__ __launch_bounds__(256) void pack_v(const float* __restrict__ vraw, u16* __restrict__ Vt){
  __shared__ float part[256];
  __shared__ float scl[64];
  __shared__ float tile[64][65];
  int tid = threadIdx.x;
  int kb = blockIdx.x, bh = blockIdx.y;
  int b = bh / NHEADS, h = bh - b*NHEADS;
  int kl = tid >> 2;
  int d0 = (tid & 3) * 16;
  int m = b * SEQ + kb * 64 + kl;
  float v[16]; float ss = 0.f;
  const float* src = vraw + (size_t)m * DDIM + h*64 + d0;
  #pragma unroll
  for (int i = 0; i < 16; i++){ v[i] = src[i]; ss += v[i]*v[i]; }
  part[tid] = ss;
  __syncthreads();
  if ((tid & 3) == 0){
    float s2 = part[tid] + part[tid+1] + part[tid+2] + part[tid+3];
    float sn = sqrtf(s2);
    float tv = sqrtf(1.f + s2);
    float ctv = fmaxf(tv, 1.f + 1e-7f);
    float dist = __logf(ctv + sqrtf(fmaxf(ctv*ctv - 1.f, 0.f)));
    scl[kl] = dist / fmaxf(sn, 1e-8f);
  }
  __syncthreads();
  float sc = scl[kl];
  #pragma unroll
  for (int i = 0; i < 16; i++) tile[kl][d0 + i] = v[i] * sc;
  __syncthreads();
  int dim = tid >> 2;
  int kk0 = (tid & 3) * 16;
  u16 tmp[16];
  #pragma unroll
  for (int i = 0; i < 16; i++) tmp[i] = f2bf(tile[kk0 + i][dim]);
  u16* dst = Vt + ((size_t)bh * 64 + dim) * SEQ + kb*64 + kk0;
  *(uint4*)dst       = *(const uint4*)tmp;
  *(uint4*)(dst + 8) = *(const uint4*)(tmp + 8);
}

// ---------------- fused hyperbolic attention (flash-style) ----------
__global__ __launch_bounds__(256) void attn_kernel(
    const u16* __restrict__ Q, const u16* __restrict__ K, const u16* __restrict__ Vt,
    const float* __restrict__ qt, const float* __restrict__ kt,
    float* __restrict__ agg,
    const float* __restrict__ a_raw, const float* __restrict__ t_raw, const float* __restrict__ l_raw)
{
  __shared__ float rv[4][64];
  __shared__ u16 Pl[4][16*80];
  int tid = threadIdx.x;
  int bh = blockIdx.y;
  int qbase = blockIdx.x * 64;
  float alpha = __logf(1.f + __expf(a_raw[0]));
  float tau   = __logf(1.f + __expf(t_raw[0]));
  float lam   = __logf(1.f + __expf(l_raw[0]));
  if (tid < 64){
    float qtv = qt[bh * SEQ + qbase + tid];
    float cq = fmaxf(qtv, 1.f + 1e-7f);
    float ct = fminf(__logf(cq + sqrtf(fmaxf(cq*cq - 1.f, 0.f))), 40.f);
    float e = __expf(ct);
    float sh = 0.5f * (e - 1.f/e);
    rv[0][tid] = qtv;
    rv[1][tid] = cq;
    rv[2][tid] = 1.f / sh;
    float ac = alpha * ct;
    rv[3][tid] = ac / (1.f + ac);
  }
  __syncthreads();
  int wave = tid >> 6, lane = tid & 63;
  int lrow = lane & 15, lq = lane >> 4;
  int rbase = qbase + wave * 16;
  const u16* Qb = Q + ((size_t)bh * SEQ + rbase + lrow) * 64 + lq*8;
  bf16x8 a0 = *(const bf16x8*)Qb;
  bf16x8 a1 = *(const bf16x8*)(Qb + 32);
  float rqt[4], rcq[4], rri[4], rB[4];
  #pragma unroll
  for (int r = 0; r < 4; r++){
    int row = wave*16 + lq*4 + r;
    rqt[r] = rv[0][row]; rcq[r] = rv[1][row]; rri[r] = rv[2][row]; rB[r] = rv[3][row];
  }
  f32x4 o[4] = {};
  float den[4] = {0.f, 0.f, 0.f, 0.f};
  const float spm = 0.64439666f;  // softplus(-0.1)
  for (int jt = 0; jt < 16; jt++){
    int jbase = jt * 64;
    const u16* Kb = K + ((size_t)bh * SEQ + jbase + lrow) * 64 + lq*8;
    f32x4 s[4];
    #pragma unroll
    for (int ct = 0; ct < 4; ct++){
      bf16x8 b0 = *(const bf16x8*)(Kb + ct*16*64);
      bf16x8 b1 = *(const bf16x8*)(Kb + ct*16*64 + 32);
      f32x4 z = {0.f, 0.f, 0.f, 0.f};
      z = mfma16(a0, b0, z);
      z = mfma16(a1, b1, z);
      s[ct] = z;
    }
    #pragma unroll
    for (int ct = 0; ct < 4; ct++){
      float ktv = kt[bh * SEQ + jbase + ct*16 + lrow];
      float ck = fmaxf(ktv, 1.f + 1e-7f);
      #pragma unroll
      for (int r = 0; r < 4; r++){
        float inner = s[ct][r] - rqt[r] * ktv;
        float rawc = fmaxf(-inner, 1.f);
        bool self = rawc < 1.00001f;
        float safe = self ? 2.f : rawc;
        float shqk = sqrtf(safe*safe - 1.f);     // sinh(arccosh(safe))
        float dist = __logf(safe + shqk);        // arccosh(safe)
        float Z = (rawc * rcq[r] - ck) * rri[r] / shqk;
        Z = self ? 1.f : fminf(fmaxf(Z, -1.f), 1.f);
        float dl = fminf(dist, 40.f);
        float logit = -lam * __logf(1.f + dl*dl)
                      - tau * (__logf(1.f + __expf(rB[r] + Z - 0.1f)) - spm);
        float p = __expf(logit);
        den[r] += p;
        Pl[wave][(lq*4 + r)*80 + ct*16 + lrow] = f2bf(p);
      }
    }
    #pragma unroll
    for (int kh = 0; kh < 2; kh++){
      bf16x8 ap = *(const bf16x8*)(&Pl[wave][lrow*80 + kh*32 + lq*8]);
      const u16* Vb = Vt + ((size_t)bh*64 + lrow) * SEQ + jbase + kh*32 + lq*8;
      #pragma unroll
      for (int nt = 0; nt < 4; nt++){
        bf16x8 bv = *(const bf16x8*)(Vb + nt*16*SEQ);
        o[nt] = mfma16(ap, bv, o[nt]);
      }
    }
  }
  #pragma unroll
  for (int r = 0; r < 4; r++){
    float d = den[r];
    d += __shfl_xor(d, 1, 64);
    d += __shfl_xor(d, 2, 64);
    d += __shfl_xor(d, 4, 64);
    d += __shfl_xor(d, 8, 64);
    den[r] = 1.f / (d * (1.f + 1e-8f));
  }
  #pragma unroll
  for (int nt = 0; nt < 4; nt++){
    #pragma unroll
    for (int r = 0; r < 4; r++){
      agg[((size_t)bh * SEQ + rbase + lq*4 + r) * 64 + nt*16 + lrow] = o[nt][r] * den[r];
    }
  }
}

// ---------------- expmap0 + t_new -> Wo input bf16 [m][800] ---------
__global__ __launch_bounds__(768) void expmap_pack(const float* __restrict__ agg, u16* __restrict__ O){
  __shared__ float th2[NHEADS];
  int m = blockIdx.x, tid = threadIdx.x;
  int h = tid >> 6, lane = tid & 63;
  int b = m >> 10, n = m & 1023, bh = b*NHEADS + h;
  float u = agg[((size_t)bh * SEQ + n) * 64 + lane];
  float n2 = u*u;
  #pragma unroll
  for (int off = 1; off < 64; off <<= 1) n2 += __shfl_xor(n2, off, 64);
  float nn = sqrtf(n2);
  float e = __expf(nn);
  float ch = 0.5f * (e + 1.f/e);
  float sh = 0.5f * (e - 1.f/e);
  float sc = sh / fmaxf(nn, 1e-8f);
  u16* orow = O + (size_t)m * KP1;
  orow[1 + h*64 + lane] = f2bf(u * sc);
  if (lane == 0) th2[h] = ch*ch;
  __syncthreads();
  if (tid == 0){
    float ssum = 0.f;
    #pragma unroll
    for (int i = 0; i < NHEADS; i++) ssum += th2[i];
    orow[0] = f2bf(sqrtf(ssum - 11.f));
  }
  if (tid >= 1 && tid < 32) orow[768 + tid] = 0;
}

// ---------------- exact GELU + add_time -> bf16 [m][3104] -----------
__global__ __launch_bounds__(256) void gelu_pack(const float* __restrict__ Zin, u16* __restrict__ O){
  __shared__ float red[4];
  int m = blockIdx.x, tid = threadIdx.x;
  const float* zr = Zin + (size_t)m * MLPD;
  float gv[12]; float gs = 0.f;
  #pragma unroll
  for (int j = 0; j < 12; j++){
    float z = zr[tid + j*256];
    float e = 0.5f * z * (1.f + erff(z * 0.70710678f));
    gv[j] = e; gs += e*e;
  }
  gs = blk_reduce(gs, red, tid);
  u16* orow = O + (size_t)m * KP2;
  #pragma unroll
  for (int j = 0; j < 12; j++) orow[1 + tid + j*256] = f2bf(gv[j]);
  if (tid == 0) orow[0] = f2bf(sqrtf(1.f + gs));
  if (tid < 31) orow[3073 + tid] = 0;
}

// ---------------- final add_time -> d_out fp32 [m][769] -------------
__global__ __launch_bounds__(256) void final_k(const float* __restrict__ Y, float* __restrict__ out){
  __shared__ float red[4];
  int m = blockIdx.x, tid = threadIdx.x;
  float v[3]; float s2 = 0.f;
  #pragma unroll
  for (int j = 0; j < 3; j++){ v[j] = Y[(size_t)m*DDIM + tid + j*256]; s2 += v[j]*v[j]; }
  s2 = blk_reduce(s2, red, tid);
  float* orow = out + (size_t)m * HID;
  if (tid == 0) orow[0] = sqrtf(1.f + s2);
  #pragma unroll
  for (int j = 0; j < 3; j++) orow[1 + tid + j*256] = v[j];
}

extern "C" void kernel_launch(void* const* d_in, const int* in_sizes, int n_in,
                              void* d_out, int out_size, void* d_ws, size_t ws_size,
                              hipStream_t stream)
{
  (void)in_sizes; (void)n_in; (void)out_size; (void)ws_size;
  const float* x   = (const float*)d_in[0];
  const float* Wq  = (const float*)d_in[1];
  const float* Wk  = (const float*)d_in[2];
  const float* Wv  = (const float*)d_in[3];
  const float* Wo  = (const float*)d_in[4];
  const float* g1p = (const float*)d_in[5];
  const float* b1p = (const float*)d_in[6];
  const float* g2p = (const float*)d_in[7];
  const float* b2p = (const float*)d_in[8];
  const float* Wm1 = (const float*)d_in[9];
  const float* Wm2 = (const float*)d_in[10];
  const float* ar  = (const float*)d_in[11];
  const float* tr  = (const float*)d_in[12];
  const float* lr  = (const float*)d_in[13];

  char* ws = (char*)d_ws;
  u16*   xln  = (u16*)(ws + 0);
  u16*   wqb  = (u16*)(ws + 6553600);
  u16*   wkb  = (u16*)(ws + 7782400);
  u16*   wvb  = (u16*)(ws + 9011200);
  u16*   wob  = (u16*)(ws + 10240000);
  u16*   wm1b = (u16*)(ws + 11468800);
  u16*   wm2b = (u16*)(ws + 16384000);
  float* qkv  = (float*)(ws + 21151744);
  u16*   qp   = (u16*)(ws + 58900480);
  u16*   kpk  = (u16*)(ws + 65191936);
  u16*   vt   = (u16*)(ws + 71483392);
  float* qtb  = (float*)(ws + 77774848);
  float* ktb  = (float*)(ws + 77971456);
  float* agg  = (float*)(ws + 78168064);
  u16*   woin = (u16*)(ws + 90750976);
  float* out1 = (float*)(ws + 97304576);
  u16*   ln2b = (u16*)(ws + 109887488);
  float* mlp1 = (float*)(ws + 21151744);   // alias: qkv (dead by then)
  u16*   g1b  = (u16*)(ws + 71483392);     // alias: vt..woin (dead by then)
  float* out2 = (float*)(ws + 0);          // alias: xln..wm1 (dead by then)

  convert_w<<<dim3((768*800+255)/256),  256, 0, stream>>>(Wq,  wqb,  768,  769,  800);
  convert_w<<<dim3((768*800+255)/256),  256, 0, stream>>>(Wk,  wkb,  768,  769,  800);
  convert_w<<<dim3((768*800+255)/256),  256, 0, stream>>>(Wv,  wvb,  768,  769,  800);
  convert_w<<<dim3((768*800+255)/256),  256, 0, stream>>>(Wo,  wob,  768,  769,  800);
  convert_w<<<dim3((3072*800+255)/256), 256, 0, stream>>>(Wm1, wm1b, 3072, 769,  800);
  convert_w<<<dim3((768*3104+255)/256), 256, 0, stream>>>(Wm2, wm2b, 768,  3073, 3104);

  ln_kernel<<<dim3(4096), 256, 0, stream>>>(x, 769, 1, g1p, b1p, xln);
  gemm128<<<dim3(6, 32, 3), 256, 0, stream>>>(xln, wqb, wkb, wvb, qkv, nullptr, 768, 800, 0, 0);
  pack_qk<<<dim3(1024, 12, 2), 256, 0, stream>>>(qkv, qp, kpk, qtb, ktb);
  pack_v<<<dim3(16, 48), 256, 0, stream>>>(qkv + (size_t)2*MROWS*DDIM, vt);
  attn_kernel<<<dim3(16, 48), 256, 0, stream>>>(qp, kpk, vt, qtb, ktb, agg, ar, tr, lr);
  expmap_pack<<<dim3(4096), 768, 0, stream>>>(agg, woin);
  gemm128<<<dim3(6, 32, 1), 256, 0, stream>>>(woin, wob, wob, wob, out1, x, 768, 800, 769, 1);
  ln_kernel<<<dim3(4096), 256, 0, stream>>>(out1, 768, 0, g2p, b2p, ln2b);
  gemm128<<<dim3(24, 32, 1), 256, 0, stream>>>(ln2b, wm1b, wm1b, wm1b, mlp1, nullptr, 3072, 800, 0, 0);
  gelu_pack<<<dim3(4096), 256, 0, stream>>>(mlp1, g1b);
  gemm128<<<dim3(6, 32, 1), 256, 0, stream>>>(g1b, wm2b, wm2b, wm2b, out2, out1, 768, 3104, 768, 0);
  final_k<<<dim3(4096), 256, 0, stream>>>(out2, (float*)d_out);
}

// Round 3
// 424.711 us; speedup vs baseline: 1.2650x; 1.2650x over previous
//
#include <hip/hip_runtime.h>
#include <cstdint>
#include <cstddef>

typedef unsigned short u16;
typedef __attribute__((ext_vector_type(8))) __bf16 bf16x8;
typedef __attribute__((ext_vector_type(4))) float f32x4;

#define SEQ 1024
#define MROWS 4096
#define DDIM 768
#define HID 769
#define KP1 800
#define MLPD 3072
#define KP2 3104
#define NHEADS 12
#define LN2F 0.69314718056f
#define LOG2EF 1.44269504089f

static __device__ __forceinline__ u16 f2bf(float f){
  union { float f; uint32_t u; } v; v.f = f;
  return (u16)((v.u + 0x7FFFu + ((v.u >> 16) & 1u)) >> 16);
}

static __device__ __forceinline__ f32x4 mfma16(bf16x8 a, bf16x8 b, f32x4 c){
  return __builtin_amdgcn_mfma_f32_16x16x32_bf16(a, b, c, 0, 0, 0);
}

static __device__ __forceinline__ void async_lds16(const u16* g, u16* l){
  u16* gm = const_cast<u16*>(g);
  __builtin_amdgcn_global_load_lds(
      (__attribute__((address_space(1))) void*)gm,
      (__attribute__((address_space(3))) void*)l, 16, 0, 0);
}

static __device__ __forceinline__ float blk_reduce(float v, float* red, int tid){
  #pragma unroll
  for (int off = 1; off < 64; off <<= 1) v += __shfl_xor(v, off, 64);
  __syncthreads();
  if ((tid & 63) == 0) red[tid >> 6] = v;
  __syncthreads();
  return red[0] + red[1] + red[2] + red[3];
}

// ---------------- all weight conversions in ONE kernel --------------
static __device__ __forceinline__ void conv_seg(const float* W, u16* O, int idx, int K, int Kp){
  int n = idx / Kp, k = idx - n * Kp;
  O[idx] = (k < K) ? f2bf(W[(size_t)n * K + k]) : (u16)0;
}
__global__ __launch_bounds__(256) void conv_all(const float* __restrict__ Wq, const float* __restrict__ Wk,
    const float* __restrict__ Wv, const float* __restrict__ Wo,
    const float* __restrict__ Wm1, const float* __restrict__ Wm2, u16* __restrict__ dst){
  int b = blockIdx.x, tid = threadIdx.x;
  if (b < 2400){        conv_seg(Wq,  dst,            b*256+tid,        769, 800); }
  else if (b < 4800){   conv_seg(Wk,  dst + 614400,  (b-2400)*256+tid,  769, 800); }
  else if (b < 7200){   conv_seg(Wv,  dst + 1228800, (b-4800)*256+tid,  769, 800); }
  else if (b < 9600){   conv_seg(Wo,  dst + 1843200, (b-7200)*256+tid,  769, 800); }
  else if (b < 19200){  conv_seg(Wm1, dst + 2457600, (b-9600)*256+tid,  769, 800); }
  else {                conv_seg(Wm2, dst + 4915200, (b-19200)*256+tid, 3073, 3104); }
}

// ---------------- lorentz layernorm -> bf16 [m][800] (col0 = t) -----
__global__ __launch_bounds__(256) void ln_kernel(const float* __restrict__ X, int xstr, int xoff,
    const float* __restrict__ g, const float* __restrict__ b, u16* __restrict__ O){
  __shared__ float red[4];
  int m = blockIdx.x, tid = threadIdx.x;
  const float* xr = X + (size_t)m * xstr + xoff;
  float s[3], y[3];
  float s1 = 0.f, s2 = 0.f;
  #pragma unroll
  for (int j = 0; j < 3; j++){ float v = xr[tid + j*256]; s[j] = v; s1 += v; s2 += v*v; }
  s1 = blk_reduce(s1, red, tid);
  s2 = blk_reduce(s2, red, tid);
  float mu = s1 * (1.f/768.f);
  float var = s2 * (1.f/768.f) - mu*mu;
  float rstd = rsqrtf(var + 1e-5f);
  float q = 0.f;
  #pragma unroll
  for (int j = 0; j < 3; j++){ int i = tid + j*256; y[j] = (s[j]-mu)*rstd*g[i] + b[i]; q += y[j]*y[j]; }
  q = blk_reduce(q, red, tid);
  u16* orow = O + (size_t)m * KP1;
  #pragma unroll
  for (int j = 0; j < 3; j++) orow[1 + tid + j*256] = f2bf(y[j]);
  if (tid == 0) orow[0] = f2bf(sqrtf(1.f + q));
  if (tid < 31) orow[769 + tid] = 0;
}

// ---------------- sum 4 partials + residual, then lorentz LN --------
__global__ __launch_bounds__(256) void ln_sum_kernel(const float* __restrict__ P4,
    const float* __restrict__ x, const float* __restrict__ g, const float* __restrict__ b,
    float* __restrict__ out1, u16* __restrict__ O){
  __shared__ float red[4];
  int m = blockIdx.x, tid = threadIdx.x;
  float s[3], y[3];
  float s1 = 0.f, s2 = 0.f;
  #pragma unroll
  for (int j = 0; j < 3; j++){
    int col = tid + j*256;
    float v = x[(size_t)m * HID + 1 + col];
    #pragma unroll
    for (int z = 0; z < 4; z++) v += P4[(size_t)z*MROWS*DDIM + (size_t)m*DDIM + col];
    out1[(size_t)m*DDIM + col] = v;
    s[j] = v; s1 += v; s2 += v*v;
  }
  s1 = blk_reduce(s1, red, tid);
  s2 = blk_reduce(s2, red, tid);
  float mu = s1 * (1.f/768.f);
  float var = s2 * (1.f/768.f) - mu*mu;
  float rstd = rsqrtf(var + 1e-5f);
  float q = 0.f;
  #pragma unroll
  for (int j = 0; j < 3; j++){ int i = tid + j*256; y[j] = (s[j]-mu)*rstd*g[i] + b[i]; q += y[j]*y[j]; }
  q = blk_reduce(q, red, tid);
  u16* orow = O + (size_t)m * KP1;
  #pragma unroll
  for (int j = 0; j < 3; j++) orow[1 + tid + j*256] = f2bf(y[j]);
  if (tid == 0) orow[0] = f2bf(sqrtf(1.f + q));
  if (tid < 31) orow[769 + tid] = 0;
}

// ---------------- 128x128 bf16 GEMM, 3 B-matrices via z -------------
__global__ __launch_bounds__(256) void gemm_qkv(
    const u16* __restrict__ A,
    const u16* __restrict__ B0, const u16* __restrict__ B1, const u16* __restrict__ B2,
    float* __restrict__ C, int N, int Kp)
{
  __shared__ u16 As[128*32];
  __shared__ u16 Bs[128*32];
  int tid = threadIdx.x;
  int wave = tid >> 6, lane = tid & 63;
  int lrow = lane & 15, lq = lane >> 4;
  int m0 = blockIdx.y * 128, n0 = blockIdx.x * 128;
  int wm = wave >> 1, wn = wave & 1;
  const u16* B = (blockIdx.z == 0) ? B0 : (blockIdx.z == 1 ? B1 : B2);
  C += (size_t)blockIdx.z * MROWS * N;
  f32x4 acc[4][4] = {};
  int seg = wave * 2;
  int srow = lane >> 2;
  int scol = (lane & 3) * 8;
  const u16* Abase = A + (size_t)m0 * Kp;
  const u16* Bbase = B + (size_t)n0 * Kp;
  for (int k0 = 0; k0 < Kp; k0 += 32){
    __syncthreads();
    #pragma unroll
    for (int i = 0; i < 2; i++){
      int s = seg + i;
      async_lds16(Abase + (size_t)(s*16 + srow) * Kp + k0 + scol, As + s*512);
      async_lds16(Bbase + (size_t)(s*16 + srow) * Kp + k0 + scol, Bs + s*512);
    }
    __syncthreads();
    bf16x8 af[4], bfr[4];
    #pragma unroll
    for (int t = 0; t < 4; t++){
      af[t]  = *(const bf16x8*)(As + (wm*64 + t*16 + lrow)*32 + lq*8);
      bfr[t] = *(const bf16x8*)(Bs + (wn*64 + t*16 + lrow)*32 + lq*8);
    }
    #pragma unroll
    for (int mt = 0; mt < 4; mt++)
      #pragma unroll
      for (int nt = 0; nt < 4; nt++)
        acc[mt][nt] = mfma16(af[mt], bfr[nt], acc[mt][nt]);
  }
  #pragma unroll
  for (int mt = 0; mt < 4; mt++)
    #pragma unroll
    for (int nt = 0; nt < 4; nt++){
      int col = n0 + wn*64 + nt*16 + lrow;
      #pragma unroll
      for (int r = 0; r < 4; r++){
        int row = m0 + wm*64 + mt*16 + lq*4 + r;
        C[(size_t)row * N + col] = acc[mt][nt][r];
      }
    }
}

// ---------------- 128x128 bf16 GEMM, split-K via z ------------------
__global__ __launch_bounds__(256) void gemm_split(
    const u16* __restrict__ A, const u16* __restrict__ B, float* __restrict__ C,
    int N, int Kp)
{
  __shared__ u16 As[128*32];
  __shared__ u16 Bs[128*32];
  int tid = threadIdx.x;
  int wave = tid >> 6, lane = tid & 63;
  int lrow = lane & 15, lq = lane >> 4;
  int m0 = blockIdx.y * 128, n0 = blockIdx.x * 128;
  int wm = wave >> 1, wn = wave & 1;
  int chunks = Kp >> 5;
  int nz = gridDim.z, z = blockIdx.z;
  int base = chunks / nz, rem = chunks - base * nz;
  int begin = z * base + (z < rem ? z : rem);
  int count = base + (z < rem ? 1 : 0);
  C += (size_t)z * MROWS * N;
  f32x4 acc[4][4] = {};
  int seg = wave * 2;
  int srow = lane >> 2;
  int scol = (lane & 3) * 8;
  const u16* Abase = A + (size_t)m0 * Kp;
  const u16* Bbase = B + (size_t)n0 * Kp;
  for (int kc = begin; kc < begin + count; kc++){
    int k0 = kc * 32;
    __syncthreads();
    #pragma unroll
    for (int i = 0; i < 2; i++){
      int s = seg + i;
      async_lds16(Abase + (size_t)(s*16 + srow) * Kp + k0 + scol, As + s*512);
      async_lds16(Bbase + (size_t)(s*16 + srow) * Kp + k0 + scol, Bs + s*512);
    }
    __syncthreads();
    bf16x8 af[4], bfr[4];
    #pragma unroll
    for (int t = 0; t < 4; t++){
      af[t]  = *(const bf16x8*)(As + (wm*64 + t*16 + lrow)*32 + lq*8);
      bfr[t] = *(const bf16x8*)(Bs + (wn*64 + t*16 + lrow)*32 + lq*8);
    }
    #pragma unroll
    for (int mt = 0; mt < 4; mt++)
      #pragma unroll
      for (int nt = 0; nt < 4; nt++)
        acc[mt][nt] = mfma16(af[mt], bfr[nt], acc[mt][nt]);
  }
  #pragma unroll
  for (int mt = 0; mt < 4; mt++)
    #pragma unroll
    for (int nt = 0; nt < 4; nt++){
      int col = n0 + wn*64 + nt*16 + lrow;
      #pragma unroll
      for (int r = 0; r < 4; r++){
        int row = m0 + wm*64 + mt*16 + lq*4 + r;
        C[(size_t)row * N + col] = acc[mt][nt][r];
      }
    }
}

// ---------------- pack Q/K heads: bf16 [bh][n][64] + t arrays -------
__global__ __launch_bounds__(256) void pack_qk(const float* __restrict__ raw,
    u16* __restrict__ Qp, u16* __restrict__ Kpk, float* __restrict__ qt, float* __restrict__ kt)
{
  int wave = threadIdx.x >> 6, lane = threadIdx.x & 63;
  int m = blockIdx.x * 4 + wave;
  int h = blockIdx.y;
  int which = blockIdx.z;
  const float* src = raw + (size_t)which * MROWS * DDIM + (size_t)m * DDIM + h*64 + lane;
  float v = *src;
  float ss = v*v;
  #pragma unroll
  for (int off = 1; off < 64; off <<= 1) ss += __shfl_xor(ss, off, 64);
  int b = m >> 10, n = m & 1023, bh = b * NHEADS + h;
  u16* dst = (which ? Kpk : Qp) + ((size_t)bh * SEQ + n) * 64 + lane;
  *dst = f2bf(v);
  if (lane == 0) (which ? kt : qt)[bh * SEQ + n] = sqrtf(1.f + ss);
}

// ---------------- pack V: logmap0, transposed bf16 [bh][dim][key] ---
__global__ __launch_bounds__(256) void pack_v(const float* __restrict__ vraw, u16* __restrict__ Vt){
  __shared__ float part[256];
  __shared__ float scl[64];
  __shared__ float tile[64][65];
  int tid = threadIdx.x;
  int kb = blockIdx.x, bh = blockIdx.y;
  int b = bh / NHEADS, h = bh - b*NHEADS;
  int kl = tid >> 2;
  int d0 = (tid & 3) * 16;
  int m = b * SEQ + kb * 64 + kl;
  float v[16]; float ss = 0.f;
  const float* src = vraw + (size_t)m * DDIM + h*64 + d0;
  #pragma unroll
  for (int i = 0; i < 16; i++){ v[i] = src[i]; ss += v[i]*v[i]; }
  part[tid] = ss;
  __syncthreads();
  if ((tid & 3) == 0){
    float s2 = part[tid] + part[tid+1] + part[tid+2] + part[tid+3];
    float sn = sqrtf(s2);
    float tv = sqrtf(1.f + s2);
    float ctv = fmaxf(tv, 1.f + 1e-7f);
    float dist = __logf(ctv + sqrtf(fmaxf(ctv*ctv - 1.f, 0.f)));
    scl[kl] = dist / fmaxf(sn, 1e-8f);
  }
  __syncthreads();
  float sc = scl[kl];
  #pragma unroll
  for (int i = 0; i < 16; i++) tile[kl][d0 + i] = v[i] * sc;
  __syncthreads();
  int dim = tid >> 2;
  int kk0 = (tid & 3) * 16;
  u16 tmp[16];
  #pragma unroll
  for (int i = 0; i < 16; i++) tmp[i] = f2bf(tile[kk0 + i][dim]);
  u16* dst = Vt + ((size_t)bh * 64 + dim) * SEQ + kb*64 + kk0;
  *(uint4*)dst       = *(const uint4*)tmp;
  *(uint4*)(dst + 8) = *(const uint4*)(tmp + 8);
}

// ---------------- fused hyperbolic attention, S^T orientation -------
// grid (16 qblocks, 48 bh, 2 ksplit); partial sums out (no normalize).
__global__ __launch_bounds__(256) void attn_kernel(
    const u16* __restrict__ Q, const u16* __restrict__ K, const u16* __restrict__ Vt,
    const float* __restrict__ qt, const float* __restrict__ kt,
    float* __restrict__ pAgg, float* __restrict__ pDen,
    const float* __restrict__ a_raw, const float* __restrict__ t_raw, const float* __restrict__ l_raw)
{
  __shared__ float rv[4][64];
  __shared__ u16 Pl[4][16*72];
  int tid = threadIdx.x;
  int bh = blockIdx.y, ks = blockIdx.z;
  int qbase = blockIdx.x * 64;
  float alpha = __logf(1.f + __expf(a_raw[0]));
  float tau   = __logf(1.f + __expf(t_raw[0]));
  float lam   = __logf(1.f + __expf(l_raw[0]));
  if (tid < 64){
    float qtv = qt[bh * SEQ + qbase + tid];
    float cq = fmaxf(qtv, 1.f + 1e-7f);
    float A = cq + __builtin_amdgcn_sqrtf(fmaxf(cq*cq - 1.f, 0.f)); // e^arccosh(cq)
    float ct = fminf(__builtin_amdgcn_logf(A) * LN2F, 40.f);
    float e = __expf(ct);
    float sh = 0.5f * (e - __builtin_amdgcn_rcpf(e));
    float ac = alpha * ct;
    rv[0][tid] = qtv;
    rv[1][tid] = cq;
    rv[2][tid] = __builtin_amdgcn_rcpf(sh);
    rv[3][tid] = (ac * __builtin_amdgcn_rcpf(1.f + ac) - 0.1f) * LOG2EF; // (B-0.1)*log2e
  }
  __syncthreads();
  int wave = tid >> 6, lane = tid & 63;
  int lrow = lane & 15, lq = lane >> 4;
  int myrow = wave*16 + lrow;
  float qt_l = rv[0][myrow], cq_l = rv[1][myrow], rri_l = rv[2][myrow], Bw_l = rv[3][myrow];
  const float tbase = tau * 0.92967051f;  // tau * softplus(-0.1)*log2e
  // Q as B-operand: rows = this wave's 16 q-rows
  const u16* Qb = Q + ((size_t)bh * SEQ + qbase + wave*16 + lrow) * 64 + lq*8;
  bf16x8 bq0 = *(const bf16x8*)Qb;
  bf16x8 bq1 = *(const bf16x8*)(Qb + 32);
  const u16* Kh = K + (size_t)bh * SEQ * 64;
  const u16* Vh = Vt + (size_t)bh * 64 * SEQ;
  const float* ktp = kt + (size_t)bh * SEQ;
  u16* Pw = &Pl[wave][0];
  f32x4 o[4] = {};
  float dsum = 0.f;
  for (int jt = 0; jt < 8; jt++){
    int jbase = ks * 512 + jt * 64;
    f32x4 s[4];
    #pragma unroll
    for (int ct = 0; ct < 4; ct++){
      const u16* Ka = Kh + (size_t)(jbase + ct*16 + lrow) * 64 + lq*8;
      bf16x8 a0 = *(const bf16x8*)Ka;
      bf16x8 a1 = *(const bf16x8*)(Ka + 32);
      f32x4 z = {0.f, 0.f, 0.f, 0.f};
      z = mfma16(a0, bq0, z);
      z = mfma16(a1, bq1, z);
      s[ct] = z;    // D[key = lq*4+r][qrow = lrow]
    }
    #pragma unroll
    for (int ct = 0; ct < 4; ct++){
      float4 kv = *(const float4*)(ktp + jbase + ct*16 + lq*4);
      uint32_t pu[4];
      #pragma unroll
      for (int r = 0; r < 4; r++){
        float ktv = (r == 0) ? kv.x : (r == 1) ? kv.y : (r == 2) ? kv.z : kv.w;
        float c = fmaxf(__builtin_fmaf(qt_l, ktv, -s[ct][r]), 1.f);
        bool self = c < 1.00001f;
        float ce = self ? 2.f : c;
        float cm1 = __builtin_fmaf(ce, ce, -1.f);
        float rs = __builtin_amdgcn_rsqf(cm1);
        float shq = cm1 * rs;                       // sinh(arccosh(ce))
        float d = fminf(__builtin_amdgcn_logf(ce + shq) * LN2F, 40.f);  // arccosh(ce), d_L clamp
        float L1 = __builtin_amdgcn_logf(__builtin_fmaf(d, d, 1.f));
        float Z = __builtin_fmaf(ce, cq_l, -ktv) * rri_l * rs;
        Z = fminf(fmaxf(Z, -1.f), 1.f);
        Z = self ? 1.f : Z;
        float w2 = __builtin_fmaf(Z, LOG2EF, Bw_l);
        float ew = __builtin_amdgcn_exp2f(w2);
        float L2 = __builtin_amdgcn_logf(ew + 1.f);
        float logit = __builtin_fmaf(-lam, L1, __builtin_fmaf(-tau, L2, tbase));
        float p = __builtin_amdgcn_exp2f(logit);
        uint32_t u = __float_as_uint(p);
        pu[r] = u;
        dsum += __uint_as_float(u & 0xFFFF0000u);   // den over truncated weights
      }
      uint32_t lo = __builtin_amdgcn_perm(pu[1], pu[0], 0x07060302u);
      uint32_t hi = __builtin_amdgcn_perm(pu[3], pu[2], 0x07060302u);
      uint2 pk; pk.x = lo; pk.y = hi;
      *(uint2*)(Pw + lrow*72 + ct*16 + lq*4) = pk;  // P[qrow][key], b64, conflict-free
    }
    // read back P as A-operand [qrow = lane&15][key chunks]
    bf16x8 ap0 = *(const bf16x8*)(Pw + lrow*72 + lq*8);
    bf16x8 ap1 = *(const bf16x8*)(Pw + lrow*72 + 32 + lq*8);
    #pragma unroll
    for (int nt = 0; nt < 4; nt++){
      const u16* Vb = Vh + (size_t)(nt*16 + lrow) * SEQ + jbase + lq*8;
      bf16x8 bv0 = *(const bf16x8*)Vb;
      bf16x8 bv1 = *(const bf16x8*)(Vb + 32);
      o[nt] = mfma16(ap0, bv0, o[nt]);
      o[nt] = mfma16(ap1, bv1, o[nt]);
    }
  }
  // den: reduce over lq groups (same qrow in lanes lrow, lrow+16, +32, +48)
  dsum += __shfl_xor(dsum, 16, 64);
  dsum += __shfl_xor(dsum, 32, 64);
  size_t pbase = ((size_t)(ks*48 + bh) * SEQ) + qbase;
  if (lq == 0) pDen[pbase + wave*16 + lrow] = dsum;
  #pragma unroll
  for (int nt = 0; nt < 4; nt++)
    #pragma unroll
    for (int r = 0; r < 4; r++)
      pAgg[(pbase + wave*16 + lq*4 + r) * 64 + nt*16 + lrow] = o[nt][r];
}

// ---------------- reduce splits + expmap0 + t_new -> bf16 [m][800] --
__global__ __launch_bounds__(768) void expmap_pack(const float* __restrict__ pAgg,
    const float* __restrict__ pDen, u16* __restrict__ O){
  __shared__ float th2[NHEADS];
  int m = blockIdx.x, tid = threadIdx.x;
  int h = tid >> 6, lane = tid & 63;
  int b = m >> 10, n = m & 1023, bh = b*NHEADS + h;
  size_t i0 = ((size_t)bh * SEQ + n);
  size_t i1 = ((size_t)(48 + bh) * SEQ + n);
  float d = pDen[i0] + pDen[i1];
  float rden = __builtin_amdgcn_rcpf(d * (1.f + 1e-8f));
  float u = (pAgg[i0*64 + lane] + pAgg[i1*64 + lane]) * rden;
  float n2 = u*u;
  #pragma unroll
  for (int off = 1; off < 64; off <<= 1) n2 += __shfl_xor(n2, off, 64);
  float nn = sqrtf(n2);
  float e = __expf(nn);
  float ch = 0.5f * (e + 1.f/e);
  float sh = 0.5f * (e - 1.f/e);
  float sc = sh / fmaxf(nn, 1e-8f);
  u16* orow = O + (size_t)m * KP1;
  orow[1 + h*64 + lane] = f2bf(u * sc);
  if (lane == 0) th2[h] = ch*ch;
  __syncthreads();
  if (tid == 0){
    float ssum = 0.f;
    #pragma unroll
    for (int i = 0; i < NHEADS; i++) ssum += th2[i];
    orow[0] = f2bf(sqrtf(ssum - 11.f));
  }
  if (tid >= 1 && tid < 32) orow[768 + tid] = 0;
}

// ---------------- exact GELU + add_time -> bf16 [m][3104] -----------
__global__ __launch_bounds__(256) void gelu_pack(const float* __restrict__ Zin, u16* __restrict__ O){
  __shared__ float red[4];
  int m = blockIdx.x, tid = threadIdx.x;
  const float* zr = Zin + (size_t)m * MLPD;
  float gv[12]; float gs = 0.f;
  #pragma unroll
  for (int j = 0; j < 12; j++){
    float z = zr[tid + j*256];
    float e = 0.5f * z * (1.f + erff(z * 0.70710678f));
    gv[j] = e; gs += e*e;
  }
  gs = blk_reduce(gs, red, tid);
  u16* orow = O + (size_t)m * KP2;
  #pragma unroll
  for (int j = 0; j < 12; j++) orow[1 + tid + j*256] = f2bf(gv[j]);
  if (tid == 0) orow[0] = f2bf(sqrtf(1.f + gs));
  if (tid < 31) orow[3073 + tid] = 0;
}

// ---------------- sum 4 partials + residual + add_time -> d_out -----
__global__ __launch_bounds__(256) void final_sum(const float* __restrict__ P4,
    const float* __restrict__ out1, float* __restrict__ out){
  __shared__ float red[4];
  int m = blockIdx.x, tid = threadIdx.x;
  float v[3]; float s2 = 0.f;
  #pragma unroll
  for (int j = 0; j < 3; j++){
    int col = tid + j*256;
    float t = out1[(size_t)m*DDIM + col];
    #pragma unroll
    for (int z = 0; z < 4; z++) t += P4[(size_t)z*MROWS*DDIM + (size_t)m*DDIM + col];
    v[j] = t; s2 += t*t;
  }
  s2 = blk_reduce(s2, red, tid);
  float* orow = out + (size_t)m * HID;
  if (tid == 0) orow[0] = sqrtf(1.f + s2);
  #pragma unroll
  for (int j = 0; j < 3; j++) orow[1 + tid + j*256] = v[j];
}

extern "C" void kernel_launch(void* const* d_in, const int* in_sizes, int n_in,
                              void* d_out, int out_size, void* d_ws, size_t ws_size,
                              hipStream_t stream)
{
  (void)in_sizes; (void)n_in; (void)out_size; (void)ws_size;
  const float* x   = (const float*)d_in[0];
  const float* Wq  = (const float*)d_in[1];
  const float* Wk  = (const float*)d_in[2];
  const float* Wv  = (const float*)d_in[3];
  const float* Wo  = (const float*)d_in[4];
  const float* g1p = (const float*)d_in[5];
  const float* b1p = (const float*)d_in[6];
  const float* g2p = (const float*)d_in[7];
  const float* b2p = (const float*)d_in[8];
  const float* Wm1 = (const float*)d_in[9];
  const float* Wm2 = (const float*)d_in[10];
  const float* ar  = (const float*)d_in[11];
  const float* tr  = (const float*)d_in[12];
  const float* lr  = (const float*)d_in[13];

  char* ws = (char*)d_ws;
  u16*   wqb  = (u16*)(ws + 0);
  u16*   wkb  = (u16*)(ws + 1228800);
  u16*   wvb  = (u16*)(ws + 2457600);
  u16*   wob  = (u16*)(ws + 3686400);
  u16*   wm1b = (u16*)(ws + 4915200);
  u16*   wm2b = (u16*)(ws + 9830400);
  u16*   xln  = (u16*)(ws + 14598144);
  float* qkv  = (float*)(ws + 21151744);   // 37.75 MB
  u16*   qp   = (u16*)(ws + 58900480);
  u16*   kpk  = (u16*)(ws + 65191936);
  u16*   vt   = (u16*)(ws + 71483392);
  float* qtb  = (float*)(ws + 77774848);
  float* ktb  = (float*)(ws + 77971456);
  float* pAgg = (float*)(ws + 78168064);   // 2 x 12.58 MB
  float* pDen = (float*)(ws + 103333888);  // 2 x 192 KB
  u16*   woin = (u16*)(ws + 103727104);    // 6.55 MB
  float* woP  = (float*)(ws + 21151744);   // alias qkv+qp+kpk (dead), 4 x 12.58
  float* out1 = (float*)(ws + 78168064);   // alias pAgg (dead), 12.58
  u16*   ln2b = (u16*)(ws + 90750976);     // 6.55
  float* mlp1 = (float*)(ws + 21151744);   // alias woP (dead), 50.3
  u16*   g1b  = (u16*)(ws + 90750976);     // alias ln2b+ (dead), 25.4
  float* out2P= (float*)(ws + 21151744);   // alias mlp1 (dead), 50.3

  conv_all<<<dim3(28512), 256, 0, stream>>>(Wq, Wk, Wv, Wo, Wm1, Wm2, wqb);
  ln_kernel<<<dim3(4096), 256, 0, stream>>>(x, 769, 1, g1p, b1p, xln);
  gemm_qkv<<<dim3(6, 32, 3), 256, 0, stream>>>(xln, wqb, wkb, wvb, qkv, 768, 800);
  pack_qk<<<dim3(1024, 12, 2), 256, 0, stream>>>(qkv, qp, kpk, qtb, ktb);
  pack_v<<<dim3(16, 48), 256, 0, stream>>>(qkv + (size_t)2*MROWS*DDIM, vt);
  attn_kernel<<<dim3(16, 48, 2), 256, 0, stream>>>(qp, kpk, vt, qtb, ktb, pAgg, pDen, ar, tr, lr);
  expmap_pack<<<dim3(4096), 768, 0, stream>>>(pAgg, pDen, woin);
  gemm_split<<<dim3(6, 32, 4), 256, 0, stream>>>(woin, wob, woP, 768, 800);
  ln_sum_kernel<<<dim3(4096), 256, 0, stream>>>(woP, x, g2p, b2p, out1, ln2b);
  gemm_split<<<dim3(24, 32, 1), 256, 0, stream>>>(ln2b, wm1b, mlp1, 3072, 800);
  gelu_pack<<<dim3(4096), 256, 0, stream>>>(mlp1, g1b);
  gemm_split<<<dim3(6, 32, 4), 256, 0, stream>>>(g1b, wm2b, out2P, 768, 3104);
  final_sum<<<dim3(4096), 256, 0, stream>>>(out2P, out1, (float*)d_out);
}